// Round 1
// baseline (647.380 us; speedup 1.0000x reference)
//
#include <hip/hip_runtime.h>
#include <hip/hip_bf16.h>

#define B_ 2048
#define D_ 512
#define N_ 100000
#define F_ 64
#define NEGV (-1000000.0f)

#define NKT 8      // K tiles of 64: 512/64
#define MBLK 8     // 2048/256
#define NBLK 391   // ceil(100000/256)

typedef __bf16 bfx8 __attribute__((ext_vector_type(8)));
typedef float f32x4 __attribute__((ext_vector_type(4)));
typedef unsigned short u16x8 __attribute__((ext_vector_type(8)));

static __device__ __forceinline__ unsigned short f2bf(float f) {
  unsigned u = __float_as_uint(f);
  unsigned r = (u + 0x7fffu + ((u >> 16) & 1u)) >> 16;
  return (unsigned short)r;
}
static __device__ __forceinline__ float bf2f(unsigned short u) {
  return __uint_as_float(((unsigned)u) << 16);
}

static __device__ __forceinline__ void async_copy16(const void* g, void* l) {
  __builtin_amdgcn_global_load_lds((const __attribute__((address_space(1))) void*)g,
                                   (__attribute__((address_space(3))) void*)l, 16, 0, 0);
}

// ---- targets (fp32, matches reference einsum) + out init + q->bf16 ---------
__global__ void targets_convert(const float* __restrict__ q, const float* __restrict__ rhs,
                                const int* __restrict__ queries, float* __restrict__ targets,
                                float* __restrict__ out, unsigned short* __restrict__ qb) {
  __shared__ float wsum[4];
  int b = blockIdx.x;
  int tid = threadIdx.x, lane = tid & 63, w = tid >> 6;
  int p = queries[b * 3 + 2];
  float2 v = ((const float2*)(q + (size_t)b * D_))[tid];   // 256 x 2 = 512 elems
  ushort2 o; o.x = f2bf(v.x); o.y = f2bf(v.y);
  ((ushort2*)(qb + (size_t)b * D_))[tid] = o;
  float s = v.x * rhs[(size_t)(2 * tid) * N_ + p] + v.y * rhs[(size_t)(2 * tid + 1) * N_ + p];
  for (int off = 32; off; off >>= 1) s += __shfl_down(s, off, 64);
  if (lane == 0) wsum[w] = s;
  __syncthreads();
  if (tid == 0) {
    targets[b] = wsum[0] + wsum[1] + wsum[2] + wsum[3];
    out[b] = 1.0f;
  }
}

// ---- rhs (D x N fp32) -> rt (N x D bf16), 64x64 LDS tile transpose ---------
__global__ void transpose_rhs(const float* __restrict__ rhs, unsigned short* __restrict__ rt) {
  __shared__ float tile[64][65];
  int n0 = blockIdx.x * 64, d0 = blockIdx.y * 64;
  int tid = threadIdx.x;
  if (n0 + 64 <= N_) {
#pragma unroll
    for (int p = 0; p < 4; ++p) {
      int e = p * 256 + tid;
      int d = e >> 4, c4 = e & 15;
      float4 v = *(const float4*)(rhs + (size_t)(d0 + d) * N_ + n0 + c4 * 4);
      tile[d][c4 * 4 + 0] = v.x; tile[d][c4 * 4 + 1] = v.y;
      tile[d][c4 * 4 + 2] = v.z; tile[d][c4 * 4 + 3] = v.w;
    }
  } else {
    int c = tid & 63, r4 = tid >> 6;
#pragma unroll
    for (int p = 0; p < 16; ++p) {
      int d = r4 + p * 4;
      if (n0 + c < N_) tile[d][c] = rhs[(size_t)(d0 + d) * N_ + n0 + c];
    }
  }
  __syncthreads();
#pragma unroll
  for (int p = 0; p < 4; ++p) {
    int e = p * 256 + tid;
    int n = e >> 4, dg = e & 15;
    if (n0 + n < N_) {
      ushort4 o;
      o.x = f2bf(tile[dg * 4 + 0][n]);
      o.y = f2bf(tile[dg * 4 + 1][n]);
      o.z = f2bf(tile[dg * 4 + 2][n]);
      o.w = f2bf(tile[dg * 4 + 3][n]);
      *(ushort4*)(rt + (size_t)(n0 + n) * D_ + d0 + dg * 4) = o;
    }
  }
}

// ---- main GEMM: 256x256 tile, BK=64, 8-phase counted-vmcnt schedule --------
// Schedule invariants (liveness-proved):
//  - window t (4 phases) reads buf p=t&1 (tile t); buf p^1 (tile t-1 data) is
//    fully dead during window t -> tile t+1's qA1,qA2,qB0..3 staged at ph0..ph2.
//  - each wave reads its NEAR m-half (wr=0: rows 0-63; wr=1: 192-255) in
//    ph0+ph1 only -> those quarters of buf p are dead after ph1's barrier ->
//    tile t+2's qA0,qA3 staged at ph2 (they are the 2 newest loads at the
//    window-end wait -> s_waitcnt vmcnt(2), never a mid-loop drain).
//  - LDS swizzle: 16B-unit involution idx ^= (row&7); staged via pre-swizzled
//    GLOBAL source + linear LDS dest (global_load_lds writes base+lane*16).
#define STAGE_A(u, qi) async_copy16(aSrc + (size_t)(qi) * 64 * D_ + (u) * 64, \
                                    &AsU[((u) & 1) * 16384 + (qi) * 4096 + tid * 8])
#define STAGE_B(u, qi) async_copy16(bSrcQ[qi] + (u) * 64, \
                                    &BsU[((u) & 1) * 16384 + (qi) * 4096 + tid * 8])

#define LD_A(RQU)                                                              \
  _Pragma("unroll") for (int mi = 0; mi < 4; ++mi)                             \
  _Pragma("unroll") for (int ks = 0; ks < 2; ++ks) {                           \
    int m = (RQU) * 64 + mi * 16 + l16;                                        \
    int idx = ((m * 64 + ks * 32 + quad * 8) ^ ((m & 7) << 3));                \
    af[mi][ks] = __builtin_bit_cast(bfx8, *(const u16x8*)&AsBuf[idx]);         \
  }

#define LD_B(NH)                                                               \
  _Pragma("unroll") for (int ni = 0; ni < 2; ++ni)                             \
  _Pragma("unroll") for (int ks = 0; ks < 2; ++ks) {                           \
    int n = wc * 64 + (NH) * 32 + ni * 16 + l16;                               \
    int idx = ((n * 64 + ks * 32 + quad * 8) ^ ((n & 7) << 3));                \
    bf[ni][ks] = __builtin_bit_cast(bfx8, *(const u16x8*)&BsBuf[idx]);         \
  }

#define MFMA_Q(NF, NH)                                                         \
  __builtin_amdgcn_s_setprio(1);                                               \
  _Pragma("unroll") for (int mi = 0; mi < 4; ++mi)                             \
  _Pragma("unroll") for (int ni = 0; ni < 2; ++ni)                             \
  _Pragma("unroll") for (int ks = 0; ks < 2; ++ks)                             \
    acc[NF][mi][NH][ni] = __builtin_amdgcn_mfma_f32_16x16x32_bf16(             \
        af[mi][ks], bf[ni][ks], acc[NF][mi][NH][ni], 0, 0, 0);                 \
  __builtin_amdgcn_s_setprio(0);

#define BAR()                          \
  asm volatile("" ::: "memory");       \
  __builtin_amdgcn_s_barrier();        \
  asm volatile("" ::: "memory")

__global__ void __launch_bounds__(512, 2) gemm_count(
    const unsigned short* __restrict__ qb,   // B x D bf16
    const unsigned short* __restrict__ rt,   // N x D bf16 (transposed rhs)
    const float* __restrict__ targets,
    float* __restrict__ out) {
  __shared__ __align__(128) unsigned short AsU[2 * 16384];  // 2 x 32 KB
  __shared__ __align__(128) unsigned short BsU[2 * 16384];  // 2 x 32 KB
  __shared__ float sT[256];

  int tid = threadIdx.x;
  // XCD-bijective block swizzle: XCD x owns one contiguous wgid chunk;
  // mblk = wgid%8 so resident blocks per XCD share B panels in its L2.
  int orig = blockIdx.x;
  int wgid = (orig & 7) * (MBLK * NBLK / 8) + (orig >> 3);
  int m0 = (wgid & 7) * 256;
  int n0 = (wgid >> 3) * 256;

  int w = tid >> 6, lane = tid & 63;
  int wr = w >> 2, wc = w & 3;          // 2 x 4 wave grid
  int quad = lane >> 4, l16 = lane & 15;

  if (tid < 256) sT[tid] = targets[m0 + tid];
  // retire the sT global load so it never enters our vmcnt ledger
  asm volatile("s_waitcnt vmcnt(0)" ::: "memory");

  // staging source addresses: dest is linear (tid*16B); source index is the
  // swizzle involution of the dest -> content[phys] = logical[swz(phys)]
  int l16u = tid ^ ((tid >> 3) & 7);    // 16B-unit index, bits 0-2 ^= row&7
  int srow = l16u >> 3;                 // 0..63 within a 64-row quarter
  int sk = (l16u & 7) * 8;              // element offset 0..56
  const unsigned short* aSrc = qb + (size_t)(m0 + srow) * D_ + sk;
  const unsigned short* bSrcQ[4];
#pragma unroll
  for (int qi = 0; qi < 4; ++qi) {
    int n = n0 + qi * 64 + srow;
    if (n > N_ - 1) n = N_ - 1;         // tail clamp; masked in epilogue
    bSrcQ[qi] = rt + (size_t)n * D_ + sk;
  }

  f32x4 acc[2][4][2][2];                // [near/far][mi][nh][ni]
  f32x4 z = {0.f, 0.f, 0.f, 0.f};
#pragma unroll
  for (int a0 = 0; a0 < 2; ++a0)
#pragma unroll
    for (int a1 = 0; a1 < 4; ++a1)
#pragma unroll
      for (int a2 = 0; a2 < 2; ++a2)
#pragma unroll
        for (int a3 = 0; a3 < 2; ++a3) acc[a0][a1][a2][a3] = z;

  // prologue: tile0 fully, tile1's qA0/qA3; leave the 2 newest in flight
#pragma unroll
  for (int qi = 0; qi < 4; ++qi) STAGE_A(0, qi);
#pragma unroll
  for (int qi = 0; qi < 4; ++qi) STAGE_B(0, qi);
  STAGE_A(1, 0); STAGE_A(1, 3);
  asm volatile("s_waitcnt vmcnt(2)" ::: "memory");
  BAR();

#pragma unroll 2
  for (int t = 0; t < NKT; ++t) {
    const unsigned short* AsBuf = &AsU[(t & 1) * 16384];
    const unsigned short* BsBuf = &BsU[(t & 1) * 16384];
    int u = t + 1, u2 = t + 2;
    int rquN = wr * 3, rquF = wr + 1;   // near/far 64-row quarters of this wave
    bfx8 af[4][2], bf[2][2];

    // ph0: near-A + B(nh0); stage tile u's far-A quarters (other buffer, dead)
    LD_A(rquN); LD_B(0);
    if (u < NKT) { STAGE_A(u, 1); STAGE_A(u, 2); }
    BAR();
    MFMA_Q(0, 0);
    BAR();

    // ph1: B(nh1), reuse af; stage tile u's qB0,qB1
    LD_B(1);
    if (u < NKT) { STAGE_B(u, 0); STAGE_B(u, 1); }
    BAR();
    MFMA_Q(0, 1);
    BAR();

    // ph2: far-A + B(nh0); stage tile u's qB2,qB3 then tile u2's qA0,qA3
    // (qA0/qA3 of THIS buffer are dead after ph1's barrier)
    LD_A(rquF); LD_B(0);
    if (u < NKT) { STAGE_B(u, 2); STAGE_B(u, 3); }
    if (u2 < NKT) { STAGE_A(u2, 0); STAGE_A(u2, 3); }
    BAR();
    MFMA_Q(1, 0);
    BAR();

    // ph3: B(nh1); window-end counted wait: tile u complete, u2's 2 loads may fly
    LD_B(1);
    BAR();
    MFMA_Q(1, 1);
    if (u2 < NKT) { asm volatile("s_waitcnt vmcnt(2)" ::: "memory"); }
    else          { asm volatile("s_waitcnt vmcnt(0)" ::: "memory"); }
    BAR();
  }

  // epilogue: compare vs target, reduce across l16, combine across wc
  int* scnt = (int*)BsU;                // reuse B LDS (all reads drained)
#pragma unroll
  for (int nf = 0; nf < 2; ++nf) {
    int rqu = nf ? (wr + 1) : wr * 3;
#pragma unroll
    for (int mi = 0; mi < 4; ++mi) {
#pragma unroll
      for (int reg = 0; reg < 4; ++reg) {
        int rl = rqu * 64 + mi * 16 + quad * 4 + reg;  // C/D row=(lane>>4)*4+reg
        float tg = sT[rl];
        int c = 0;
#pragma unroll
        for (int nh = 0; nh < 2; ++nh)
#pragma unroll
          for (int ni = 0; ni < 2; ++ni) {
            int col = n0 + wc * 64 + nh * 32 + ni * 16 + l16;  // C/D col=lane&15
            if (col < N_ && acc[nf][mi][nh][ni][reg] >= tg) c++;
          }
        c += __shfl_xor(c, 1, 64);
        c += __shfl_xor(c, 2, 64);
        c += __shfl_xor(c, 4, 64);
        c += __shfl_xor(c, 8, 64);
        if (l16 == 0) scnt[wc * 256 + rl] = c;   // single writer per slot
      }
    }
  }
  __syncthreads();
  if (tid < 256) {
    int tot = scnt[tid] + scnt[256 + tid] + scnt[512 + tid] + scnt[768 + tid];
    if (tot) atomicAdd(&out[m0 + tid], (float)tot);
  }
}

// ---- corrections: wave-cooperative dots over filter ∪ {true}, 8 waves ------
__global__ void corrections(const unsigned short* __restrict__ qb,
                            const unsigned short* __restrict__ rt,
                            const int* __restrict__ queries,
                            const int* __restrict__ filt,
                            const float* __restrict__ targets,
                            float* __restrict__ out) {
  int b = blockIdx.x;
  int tid = threadIdx.x;  // 512
  int w = tid >> 6, lane = tid & 63;
  __shared__ int idx[F_ + 1];
  __shared__ unsigned char uq[F_ + 1];
  if (tid <= F_) idx[tid] = (tid < F_) ? filt[b * F_ + tid] : queries[b * 3 + 2];
  __syncthreads();
  if (tid <= F_) {
    int p = idx[tid];
    bool u = true;
    for (int j = 0; j < tid; ++j)
      if (idx[j] == p) u = false;
    uq[tid] = u;
  }
  __syncthreads();
  float t = targets[b];
  float corr = 0.f;
  u16x8 qv = ((const u16x8*)(qb + (size_t)b * D_))[lane];
  for (int ii = w; ii <= F_; ii += 8) {
    if (!uq[ii]) continue;                       // wave-uniform branch
    int p = idx[ii];
    u16x8 rv = ((const u16x8*)(rt + (size_t)p * D_))[lane];
    float s = 0.f;
#pragma unroll
    for (int j = 0; j < 8; ++j) s += bf2f(qv[j]) * bf2f(rv[j]);
    for (int off = 32; off; off >>= 1) s += __shfl_down(s, off, 64);
    if (lane == 0)
      corr += (NEGV >= t ? 1.f : 0.f) - (s >= t ? 1.f : 0.f);
  }
  if (lane == 0 && corr != 0.f) atomicAdd(&out[b], corr);
}

// ---- fallback path (ws too small) ------------------------------------------
__global__ void targets_init(const float* __restrict__ q, const float* __restrict__ rhs,
                             const int* __restrict__ queries, float* __restrict__ targets,
                             float* __restrict__ out) {
  __shared__ float wsum[4];
  int b = blockIdx.x;
  int tid = threadIdx.x, lane = tid & 63, w = tid >> 6;
  int p = queries[b * 3 + 2];
  float s = 0.f;
  for (int d = tid; d < D_; d += 256) s += q[b * D_ + d] * rhs[(size_t)d * N_ + p];
  for (int off = 32; off; off >>= 1) s += __shfl_down(s, off, 64);
  if (lane == 0) wsum[w] = s;
  __syncthreads();
  if (tid == 0) {
    targets[b] = wsum[0] + wsum[1] + wsum[2] + wsum[3];
    out[b] = 1.0f;
  }
}

__global__ void fallback_count(const float* __restrict__ q, const float* __restrict__ rhs,
                               const int* __restrict__ queries, const int* __restrict__ filt,
                               const float* __restrict__ targets, float* __restrict__ out) {
  int b = blockIdx.y;
  int n = blockIdx.x * 256 + threadIdx.x;
  __shared__ float qs[D_];
  __shared__ int idx[F_ + 1];
  __shared__ int cnt;
  for (int d = threadIdx.x; d < D_; d += 256) qs[d] = q[b * D_ + d];
  if (threadIdx.x < F_) idx[threadIdx.x] = filt[b * F_ + threadIdx.x];
  if (threadIdx.x == F_) idx[F_] = queries[b * 3 + 2];
  if (threadIdx.x == 0) cnt = 0;
  __syncthreads();
  if (n < N_) {
    float t = targets[b];
    float s = 0.f;
    for (int d = 0; d < D_; ++d) s += qs[d] * rhs[(size_t)d * N_ + n];
    bool member = false;
    for (int j = 0; j <= F_; ++j)
      if (idx[j] == n) member = true;
    float sv = member ? NEGV : s;
    if (sv >= t) atomicAdd(&cnt, 1);
  }
  __syncthreads();
  if (threadIdx.x == 0 && cnt) atomicAdd(&out[b], (float)cnt);
}

extern "C" void kernel_launch(void* const* d_in, const int* in_sizes, int n_in,
                              void* d_out, int out_size, void* d_ws, size_t ws_size,
                              hipStream_t stream) {
  const float* q = (const float*)d_in[0];
  const float* rhs = (const float*)d_in[1];
  const int* queries = (const int*)d_in[2];
  const int* filt = (const int*)d_in[3];
  float* out = (float*)d_out;

  char* wsb = (char*)d_ws;
  float* targets = (float*)wsb;                                   // 8 KB
  unsigned short* qb = (unsigned short*)(wsb + 8192);             // 2 MB
  unsigned short* rt = (unsigned short*)(wsb + 8192 + (size_t)B_ * D_ * 2);  // 102.4 MB
  size_t need = 8192 + (size_t)B_ * D_ * 2 + (size_t)N_ * D_ * 2;

  if (ws_size >= need) {
    targets_convert<<<B_, 256, 0, stream>>>(q, rhs, queries, targets, out, qb);
    transpose_rhs<<<dim3((N_ + 63) / 64, D_ / 64), 256, 0, stream>>>(rhs, rt);
    gemm_count<<<MBLK * NBLK, 512, 0, stream>>>(qb, rt, targets, out);
    corrections<<<B_, 512, 0, stream>>>(qb, rt, queries, filt, targets, out);
  } else {
    targets_init<<<B_, 256, 0, stream>>>(q, rhs, queries, targets, out);
    fallback_count<<<dim3((N_ + 255) / 256, B_), 256, 0, stream>>>(q, rhs, queries, filt, targets, out);
  }
}